// Round 10
// baseline (3436.308 us; speedup 1.0000x reference)
//
#include <hip/hip_runtime.h>
#include <cstdint>
#include <cmath>

#define B_ 256
#define T_ 16
#define V_ 32000
#define E_ 256
#define H_ 512

typedef __attribute__((ext_vector_type(8))) short bf16x8;
typedef __attribute__((ext_vector_type(4))) float f32x4;

// ---------------- Threefry-2x32 (JAX-compatible) ----------------
__device__ __forceinline__ uint32_t rotl32(uint32_t x, int r) {
  return (x << r) | (x >> (32 - r));
}

__device__ __forceinline__ void tf2x32(uint32_t k0, uint32_t k1, uint32_t x0, uint32_t x1,
                                       uint32_t& o0, uint32_t& o1) {
  uint32_t k2 = k0 ^ k1 ^ 0x1BD11BDAu;
  x0 += k0; x1 += k1;
#define TFR(r) { x0 += x1; x1 = rotl32(x1, (r)); x1 ^= x0; }
  TFR(13) TFR(15) TFR(26) TFR(6)   x0 += k1; x1 += k2 + 1u;
  TFR(17) TFR(29) TFR(16) TFR(24)  x0 += k2; x1 += k0 + 2u;
  TFR(13) TFR(15) TFR(26) TFR(6)   x0 += k0; x1 += k1 + 3u;
  TFR(17) TFR(29) TFR(16) TFR(24)  x0 += k1; x1 += k2 + 4u;
  TFR(13) TFR(15) TFR(26) TFR(6)   x0 += k2; x1 += k0 + 5u;
#undef TFR
  o0 = x0; o1 = x1;
}

// round f32 -> bf16 bits (RTNE), value assumed finite
__device__ __forceinline__ uint32_t f2bf(float x) {
  uint32_t u = __float_as_uint(x);
  return (u + 0x7fffu + ((u >> 16) & 1u)) >> 16;
}

typedef const __attribute__((address_space(1))) void* as1_t;
typedef __attribute__((address_space(3))) void* as3_t;
__device__ __forceinline__ void glds16(const void* g, void* l) {
  __builtin_amdgcn_global_load_lds((as1_t)g, (as3_t)l, 16, 0, 0);
}

// ---------------- prep cell weights: bf16 [hi|lo], interleaved (j,gate) ----------------
__global__ __launch_bounds__(256) void prepW3_kernel(
    const float* __restrict__ wih, const float* __restrict__ whh,
    const float* __restrict__ bih, const float* __restrict__ bhh,
    ushort* __restrict__ W3, float* __restrict__ bq, int E, uint32_t* __restrict__ keys)
{
  const int K = E + 512;
  const long long tot = 2048LL * K;
  const long long stride = (long long)gridDim.x * blockDim.x;
  const long long i0 = (long long)blockIdx.x * blockDim.x + threadIdx.x;
  if (keys && i0 < 16) {
    uint32_t o0, o1;
    tf2x32(0u, 1u, 0u, (uint32_t)i0, o0, o1);   // split(key(1), 16)
    keys[2 * i0] = o0; keys[2 * i0 + 1] = o1;
  }
  for (long long i = i0; i < tot + 2048; i += stride) {
    if (i < tot) {
      int n = (int)(i / K), k = (int)(i % K);
      int j = n >> 2, g = n & 3;
      int r = g * 512 + j;
      float x = (k < E) ? wih[(size_t)r * E + k] : whh[(size_t)r * 512 + (k - E)];
      uint32_t hi = f2bf(x);
      float hf = __uint_as_float(hi << 16);
      uint32_t lo = f2bf(x - hf);
      ushort* row = W3 + (size_t)n * 2 * K;
      row[k] = (ushort)hi;
      row[K + k] = (ushort)lo;
    } else {
      int n = (int)(i - tot);
      int j = n >> 2, g = n & 3;
      bq[n] = bih[g * 512 + j] + bhh[g * 512 + j];
    }
  }
}

// ---------------- prep B2: out_w f32 [32000][512] -> bf16 [hi|lo] [32000][1024] ----------
__global__ __launch_bounds__(256) void prepB2_kernel(const float* __restrict__ w,
                                                     ushort* __restrict__ B2)
{
  const long long stride = (long long)gridDim.x * blockDim.x;
  for (long long i = (long long)blockIdx.x * blockDim.x + threadIdx.x;
       i < (long long)V_ * 512; i += stride) {
    int n = (int)(i >> 9), k = (int)(i & 511);
    float x = w[i];
    uint32_t hi = f2bf(x);
    float hf = __uint_as_float(hi << 16);
    uint32_t lo = f2bf(x - hf);
    ushort* row = B2 + (size_t)n * 1024;
    row[k] = (ushort)hi;
    row[512 + k] = (ushort)lo;
  }
}

// ---------------- backbone: Linear + LayerNorm + exact GELU, state init ----------------
// A0 row [x_hi(256)|h_hi(512)|x_lo(256)|h_lo(512)] stride 1536
// A1 row [h0_hi(512)|h1_hi(512)|h0_lo(512)|h1_lo(512)] stride 2048
__global__ __launch_bounds__(256) void backbone_kernel(
    const float* __restrict__ x, const float* __restrict__ bb_w, const float* __restrict__ bb_b,
    const float* __restrict__ ln_g, const float* __restrict__ ln_b, const float* __restrict__ sos,
    ushort* __restrict__ A0a, ushort* __restrict__ A1a,
    float* __restrict__ c0, float* __restrict__ c1, int* __restrict__ done)
{
  const int b = blockIdx.x, tid = threadIdx.x;
  __shared__ float xs[E_];
  __shared__ float zs[H_];
  __shared__ float red[256];
  xs[tid] = x[b * E_ + tid];
  __syncthreads();
  for (int jj = 0; jj < 2; ++jj) {
    int j = jj * 256 + tid;
    float acc = 0.0f;
#pragma unroll 4
    for (int k = 0; k < E_; ++k) acc = fmaf(xs[k], bb_w[(size_t)j * E_ + k], acc);
    zs[j] = acc + bb_b[j];
  }
  __syncthreads();
  red[tid] = zs[tid] + zs[tid + 256];
  __syncthreads();
  for (int off = 128; off > 0; off >>= 1) { if (tid < off) red[tid] += red[tid + off]; __syncthreads(); }
  const float mu = red[0] / 512.0f;
  __syncthreads();
  {
    float d0 = zs[tid] - mu, d1 = zs[tid + 256] - mu;
    red[tid] = d0 * d0 + d1 * d1;
  }
  __syncthreads();
  for (int off = 128; off > 0; off >>= 1) { if (tid < off) red[tid] += red[tid + off]; __syncthreads(); }
  const float var = red[0] / 512.0f;
  const float sv = sqrtf(var + 1e-5f);
  for (int jj = 0; jj < 2; ++jj) {
    int j = jj * 256 + tid;
    float zn = (zs[j] - mu) / sv * ln_g[j] + ln_b[j];
    float h = 0.5f * zn * (1.0f + erff(zn / 1.41421356237309515f));
    uint32_t hi = f2bf(h);
    float hf = __uint_as_float(hi << 16);
    uint32_t lo = f2bf(h - hf);
    A0a[(size_t)b * 1536 + 256 + j]  = (ushort)hi;   // h0 hi
    A0a[(size_t)b * 1536 + 1024 + j] = (ushort)lo;   // h0 lo
    A1a[(size_t)b * 2048 + 512 + j]  = 0;            // h1 hi = 0
    A1a[(size_t)b * 2048 + 1536 + j] = 0;            // h1 lo = 0
    c0[(size_t)b * 512 + j] = 0.0f;
    c1[(size_t)b * 512 + j] = 0.0f;
  }
  {
    const float xv = sos[tid];
    uint32_t hi = f2bf(xv);
    float hf = __uint_as_float(hi << 16);
    uint32_t lo = f2bf(xv - hf);
    A0a[(size_t)b * 1536 + tid]       = (ushort)hi;  // x hi
    A0a[(size_t)b * 1536 + 768 + tid] = (ushort)lo;  // x lo
  }
  if (tid == 0) done[b] = 0;
}

// ---------------- split-bf16 MFMA LSTM cell, 4-chunk rounds, double-buffered ----------------
// A3 [256][2K], W3 [2048][2K] bf16 [hi|lo]; K-chunk term map: A {hi,hi,lo}, W {hi,lo,hi}.
// 32x64 tile, grid (32,8)=256 blocks, 4 waves (2x2).
template<int TK>
__global__ __launch_bounds__(256) void mfma_lstm(
    const ushort* __restrict__ A3, const ushort* __restrict__ W3,
    const float* __restrict__ bias, float* __restrict__ c,
    ushort* __restrict__ d1, int rs1, int o1h, int o1l,
    ushort* __restrict__ d2, int rs2, int o2h, int o2l)
{
  constexpr int K = TK * 64;
  constexpr int KC = 3 * TK;
  constexpr int NR = KC / 4;                 // 9 (cell0) / 12 (cell1)
  constexpr int RS = 2 * K;                  // row stride (ushorts)
  __shared__ __align__(16) char smem[98304];
  const int tid = threadIdx.x;
  const int lane = tid & 63;
  const int wid = tid >> 6;
  const int wm = wid >> 1, wn = wid & 1;
  const int m0 = blockIdx.y * 32;
  const int n0 = blockIdx.x * 64;

  auto stage_chunk = [&](int kc, char* cbase) {
    const int tI = kc / TK;
    const int kin = kc - tI * TK;
    const int abase = (tI == 2 ? K : 0) + kin * 64;
    const int wbase = (tI == 1 ? K : 0) + kin * 64;
    {  // A tile [32][64]: 4 KB, 1 load/thread
      const int o = wid * 1024 + lane * 16;
      const int row = o >> 7;
      const int kb = (o >> 4) & 7;
      glds16(A3 + (size_t)(m0 + row) * RS + abase + ((kb ^ (row & 7)) << 3),
             (void*)(cbase + wid * 1024));
    }
#pragma unroll
    for (int s = 0; s < 2; ++s) {  // W tile [64][64]: 8 KB, 2 loads/thread
      const int o = (wid * 2 + s) * 1024 + lane * 16;
      const int row = o >> 7;
      const int kb = (o >> 4) & 7;
      glds16(W3 + (size_t)(n0 + row) * RS + wbase + ((kb ^ (row & 7)) << 3),
             (void*)(cbase + 4096 + (wid * 2 + s) * 1024));
    }
  };
  auto stage_round = [&](int r, char* base) {
#pragma unroll
    for (int cch = 0; cch < 4; ++cch) stage_chunk(r * 4 + cch, base + cch * 12288);
  };

  f32x4 acc[2];
#pragma unroll
  for (int j = 0; j < 2; ++j)
#pragma unroll
    for (int q = 0; q < 4; ++q) acc[j][q] = 0.0f;

  stage_round(0, smem);
  asm volatile("s_waitcnt vmcnt(0)" ::: "memory");
  __syncthreads();
  for (int r = 0; r < NR; ++r) {
    char* cur = smem + (r & 1) * 49152;
    if (r + 1 < NR) stage_round(r + 1, smem + ((r + 1) & 1) * 49152);
#pragma unroll
    for (int cch = 0; cch < 4; ++cch) {
      char* lds = cur + cch * 12288;
#pragma unroll
      for (int ks = 0; ks < 2; ++ks) {
        const int kb = ks * 4 + (lane >> 4);
        const int arow = wm * 16 + (lane & 15);
        bf16x8 a = *(const bf16x8*)(lds + arow * 128 + ((kb ^ (arow & 7)) << 4));
        bf16x8 w[2];
#pragma unroll
        for (int j = 0; j < 2; ++j) {
          const int col = wn * 32 + j * 16 + (lane & 15);
          w[j] = *(const bf16x8*)(lds + 4096 + col * 128 + ((kb ^ (col & 7)) << 4));
        }
#pragma unroll
        for (int j = 0; j < 2; ++j)
          acc[j] = __builtin_amdgcn_mfma_f32_16x16x32_bf16(a, w[j], acc[j], 0, 0, 0);
      }
    }
    asm volatile("s_waitcnt vmcnt(0)" ::: "memory");
    __syncthreads();
  }
  // gate transpose via LDS (f32 [32][65], aliases buf0 — all staging/compute done)
  float* gls = (float*)smem;
#pragma unroll
  for (int j = 0; j < 2; ++j)
#pragma unroll
    for (int q = 0; q < 4; ++q)
      gls[(wm * 16 + (lane >> 4) * 4 + q) * 65 + wn * 32 + j * 16 + (lane & 15)] = acc[j][q];
  __syncthreads();
  const int row = tid >> 3;                  // 0..31
  const int m = m0 + row;
#pragma unroll
  for (int e = 0; e < 2; ++e) {
    const int ul = (tid & 7) * 2 + e;        // local unit 0..15
    const int nc = ul * 4;
    const float gi = gls[row * 65 + nc + 0] + bias[n0 + nc + 0];
    const float gf = gls[row * 65 + nc + 1] + bias[n0 + nc + 1];
    const float gg = gls[row * 65 + nc + 2] + bias[n0 + nc + 2];
    const float go = gls[row * 65 + nc + 3] + bias[n0 + nc + 3];
    const int u = (n0 >> 2) + ul;            // global hidden unit
    const float si = 1.0f / (1.0f + expf(-gi));
    const float sf = 1.0f / (1.0f + expf(-gf));
    const float so = 1.0f / (1.0f + expf(-go));
    const float cn = sf * c[(size_t)m * 512 + u] + si * tanhf(gg);
    const float hn = so * tanhf(cn);
    c[(size_t)m * 512 + u] = cn;
    const uint32_t hi = f2bf(hn);
    const float hf = __uint_as_float(hi << 16);
    const uint32_t lo = f2bf(hn - hf);
    d1[(size_t)m * rs1 + o1h + u] = (ushort)hi;
    d1[(size_t)m * rs1 + o1l + u] = (ushort)lo;
    d2[(size_t)m * rs2 + o2h + u] = (ushort)hi;
    d2[(size_t)m * rs2 + o2l + u] = (ushort)lo;
  }
}

// ---------------- fused bf16 MFMA logits GEMM + PRUNED gumbel/softmax partials ------------
// A2 [256][1024] (term map {hi,hi,lo}), B2 [32000][1024] (term map {hi,lo,hi}).
// 128x128 tile, dbuf 2-phase; epilogue computes per (row, 64-col chunk):
//   S=sum exp(l), A=sum l*exp(l)  (m=0, |l| small), best (s,idx,l) with pruned gumbel.
// Pruning proof as r9: exact j=0 per 16-lane row group -> th = group max; j>=1 pruned iff
// u < exp(-exp(-(th-l-1e-3))) which implies s < th strictly (margin covers all fp error;
// uth saturating to 1.0f is safe since max achievable gumbel < 16). Logits never hit HBM.
__global__ __launch_bounds__(256) void mfma_sample(
    const ushort* __restrict__ A2,
    const ushort* __restrict__ B2,
    const float* __restrict__ bias,
    const uint32_t* __restrict__ keys, int t,
    float* __restrict__ partials)    // [256][500][8]
{
  __shared__ __align__(16) char smem[65536];
  char* lds = smem;
  const int tid = threadIdx.x;
  const int lane = tid & 63;
  const int wid = tid >> 6;
  const int wm = wid >> 1, wn = wid & 1;
  // bijective XCD swizzle (nwg=500: q=62, r=4), then m-blocks of a panel adjacent
  const int bid = blockIdx.x;
  const int xcd = bid & 7, idx = bid >> 3;
  const int wg = (xcd < 4 ? xcd * 63 : 252 + (xcd - 4) * 62) + idx;
  const int m0 = (wg & 1) * 128;
  const int n0 = (wg >> 1) * 128;

  auto stage = [&](int kc, int base) {
    const int tI = kc >> 3;
    const int kin = kc & 7;
    const int abase = (tI == 2 ? 512 : 0) + kin * 64;
    const int bbase = (tI == 1 ? 512 : 0) + kin * 64;
#pragma unroll
    for (int s = 0; s < 4; ++s) {
      const int o = (wid * 4 + s) * 1024 + lane * 16;
      const int row = o >> 7;
      const int kb = (o >> 4) & 7;
      const int sw = (kb ^ (row & 7)) << 3;
      glds16(A2 + (size_t)(m0 + row) * 1024 + abase + sw,
             (void*)(lds + base + (wid * 4 + s) * 1024));
      glds16(B2 + (size_t)(n0 + row) * 1024 + bbase + sw,
             (void*)(lds + base + 16384 + (wid * 4 + s) * 1024));
    }
  };

  f32x4 acc[4][4];
#pragma unroll
  for (int i = 0; i < 4; ++i)
#pragma unroll
    for (int j = 0; j < 4; ++j)
#pragma unroll
      for (int q = 0; q < 4; ++q) acc[i][j][q] = 0.0f;

  stage(0, 0);
  asm volatile("s_waitcnt vmcnt(0)" ::: "memory");
  __syncthreads();
  for (int kc = 0; kc < 24; ++kc) {
    const int cb = (kc & 1) * 32768;
    if (kc + 1 < 24) stage(kc + 1, cb ^ 32768);
#pragma unroll
    for (int ks = 0; ks < 2; ++ks) {
      bf16x8 a[4], b[4];
      const int kb = ks * 4 + (lane >> 4);
#pragma unroll
      for (int i = 0; i < 4; ++i) {
        const int row = wm * 64 + i * 16 + (lane & 15);
        a[i] = *(const bf16x8*)(lds + cb + row * 128 + ((kb ^ (row & 7)) << 4));
        const int col = wn * 64 + i * 16 + (lane & 15);
        b[i] = *(const bf16x8*)(lds + cb + 16384 + col * 128 + ((kb ^ (col & 7)) << 4));
      }
#pragma unroll
      for (int i = 0; i < 4; ++i)
#pragma unroll
        for (int j = 0; j < 4; ++j)
          acc[i][j] = __builtin_amdgcn_mfma_f32_16x16x32_bf16(a[i], b[j], acc[i][j], 0, 0, 0);
    }
    asm volatile("s_waitcnt vmcnt(0)" ::: "memory");
    __syncthreads();
  }

  // ---- fused pruned-gumbel sampling epilogue ----
  const uint32_t k0 = keys[2 * t], k1 = keys[2 * t + 1];
  const int lsub = lane & 15;
  float bj[4];
#pragma unroll
  for (int j = 0; j < 4; ++j) bj[j] = bias[n0 + wn * 64 + j * 16 + lsub];
  const int pidx = (n0 >> 6) + wn;           // column-chunk index 0..499
#pragma unroll
  for (int i = 0; i < 4; ++i) {
#pragma unroll
    for (int q = 0; q < 4; ++q) {
      const int m = m0 + wm * 64 + i * 16 + (lane >> 4) * 4 + q;
      float l[4];
      float S = 0.0f, Aa = 0.0f;
#pragma unroll
      for (int j = 0; j < 4; ++j) {
        l[j] = acc[i][j][q] + bj[j];
        const float ex = expf(l[j]);         // |l| small: no overflow, m=0 stats
        S += ex; Aa = fmaf(ex, l[j], Aa);
      }
      // exact gumbel for j=0 (threshold warm-up)
      float sb; int ib; float lb;
      {
        const int v = n0 + wn * 64 + lsub;
        uint32_t o0, o1;
        tf2x32(k0, k1, 0u, (uint32_t)(m * V_ + v), o0, o1);
        const uint32_t man = (o0 ^ o1) >> 9;
        const float u = (man == 0u) ? 1.17549435e-38f
                                    : __uint_as_float(man | 0x3f800000u) - 1.0f;
        const float inner = (float)log((double)u);
        const float outer = (float)log((double)(-inner));
        sb = l[0] - outer; ib = v; lb = l[0];
      }
      float th = sb;
#pragma unroll
      for (int o = 1; o < 16; o <<= 1) th = fmaxf(th, __shfl_xor(th, o, 16));
      // j = 1..3 pruned
#pragma unroll
      for (int j = 1; j < 4; ++j) {
        const int v = n0 + wn * 64 + j * 16 + lsub;
        uint32_t o0, o1;
        tf2x32(k0, k1, 0u, (uint32_t)(m * V_ + v), o0, o1);
        const uint32_t man = (o0 ^ o1) >> 9;
        const float u = (man == 0u) ? 1.17549435e-38f
                                    : __uint_as_float(man | 0x3f800000u) - 1.0f;
        const float thl = fmaxf(th, sb);
        const float uth = __expf(-__expf(-(thl - l[j] - 1e-3f)));
        if (u >= uth) {
          const float inner = (float)log((double)u);
          const float outer = (float)log((double)(-inner));
          const float s = l[j] - outer;
          if (s > sb) { sb = s; ib = v; lb = l[j]; }
        }
      }
      // 16-lane row-group reduce: sums + (max s, min idx) with carried l
#pragma unroll
      for (int o = 1; o < 16; o <<= 1) {
        S  += __shfl_xor(S, o, 16);
        Aa += __shfl_xor(Aa, o, 16);
        float s2 = __shfl_xor(sb, o, 16);
        int   i2 = __shfl_xor(ib, o, 16);
        float l2 = __shfl_xor(lb, o, 16);
        if (s2 > sb || (s2 == sb && i2 < ib)) { sb = s2; ib = i2; lb = l2; }
      }
      if (lsub == 0) {
        float* dst = partials + ((size_t)m * 500 + pidx) * 8;
        *(float4*)dst = make_float4(S, Aa, sb, __int_as_float(ib));
        dst[4] = lb;
      }
    }
  }
}

// ---------------- merge 500 partials: token, logp, entropy, feedback (+lengths @15) -------
__global__ __launch_bounds__(256) void merge_sample(
    const float* __restrict__ partials, const float* __restrict__ emb,
    int t, int* __restrict__ done, ushort* __restrict__ A0next,
    float* __restrict__ ids, float* __restrict__ logp, float* __restrict__ ent,
    float* __restrict__ lens)
{
  const int b = blockIdx.x, tid = threadIdx.x;
  float S = 0.0f, Aa = 0.0f, sb = -INFINITY, lb = 0.0f;
  int ib = 0x7fffffff;
  {
    const float* src = partials + ((size_t)b * 500 + tid) * 8;
    float4 p0 = *(const float4*)src;
    S = p0.x; Aa = p0.y; sb = p0.z; ib = __float_as_int(p0.w); lb = src[4];
  }
  if (tid + 256 < 500) {
    const float* src = partials + ((size_t)b * 500 + tid + 256) * 8;
    float4 p0 = *(const float4*)src;
    S += p0.x; Aa += p0.y;
    float s2 = p0.z; int i2 = __float_as_int(p0.w);
    if (s2 > sb || (s2 == sb && i2 < ib)) { sb = s2; ib = i2; lb = src[4]; }
  }
  __shared__ float ss[256], sa[256], sv[256], sl[256];
  __shared__ int si[256];
  ss[tid] = S; sa[tid] = Aa; sv[tid] = sb; si[tid] = ib; sl[tid] = lb;
  __syncthreads();
  for (int o = 128; o > 0; o >>= 1) {
    if (tid < o) {
      ss[tid] += ss[tid + o]; sa[tid] += sa[tid + o];
      float v2 = sv[tid + o]; int i2 = si[tid + o];
      if (v2 > sv[tid] || (v2 == sv[tid] && i2 < si[tid])) {
        sv[tid] = v2; si[tid] = i2; sl[tid] = sl[tid + o];
      }
    }
    __syncthreads();
  }
  if (tid == 0) {
    const float Sg = ss[0], Ag = sa[0];
    const float logS = logf(Sg);
    const int tok = si[0];
    const float lp = sl[0] - logS;
    const float en = logS - Ag / Sg;
    const int dn = done[b];
    const int tokm = dn ? 0 : tok;
    ids[b * T_ + t]  = (float)tokm;
    logp[b * T_ + t] = dn ? 0.0f : lp;
    ent[b * T_ + t]  = dn ? 0.0f : en;
    done[b] = dn | (tokm == 0);
    si[0] = tokm;
    if (t == T_ - 1) {
      int len = T_; bool has = false;
      for (int tt = 0; tt < T_; ++tt) {
        if (!has && ids[b * T_ + tt] == 0.0f) { has = true; len = tt + 1; }
      }
      for (int tt = len - 1; tt < T_; ++tt) ids[b * T_ + tt] = 0.0f;
      lens[b] = (float)len;
    }
  }
  __syncthreads();
  const int tk = si[0];
  {
    const float xv = emb[(size_t)tk * E_ + tid];
    const uint32_t hi = f2bf(xv);
    const float hf = __uint_as_float(hi << 16);
    const uint32_t lo = f2bf(xv - hf);
    A0next[(size_t)b * 1536 + tid]       = (ushort)hi;
    A0next[(size_t)b * 1536 + 768 + tid] = (ushort)lo;
  }
}

// ---------------- one-hot msg fill ----------------
__global__ __launch_bounds__(256) void msg_kernel(const float* __restrict__ ids,
                                                  float* __restrict__ msg) {
  const int bt = blockIdx.x;            // 4096 = B*T
  const int id = (int)ids[bt];
  float4* dst = (float4*)(msg + (size_t)bt * V_);
  for (int q = threadIdx.x; q < V_ / 4; q += 256) {
    const int v = q * 4;
    float4 val;
    val.x = (v     == id) ? 1.0f : 0.0f;
    val.y = (v + 1 == id) ? 1.0f : 0.0f;
    val.z = (v + 2 == id) ? 1.0f : 0.0f;
    val.w = (v + 3 == id) ? 1.0f : 0.0f;
    dst[q] = val;
  }
}

// ---------------- launcher ----------------
extern "C" void kernel_launch(void* const* d_in, const int* in_sizes, int n_in,
                              void* d_out, int out_size, void* d_ws, size_t ws_size,
                              hipStream_t stream) {
  const float* x    = (const float*)d_in[0];
  const float* bb_w = (const float*)d_in[1];
  const float* bb_b = (const float*)d_in[2];
  const float* ln_g = (const float*)d_in[3];
  const float* ln_b = (const float*)d_in[4];
  const float* emb  = (const float*)d_in[5];
  const float* sos  = (const float*)d_in[6];
  const float* wih0 = (const float*)d_in[7];
  const float* whh0 = (const float*)d_in[8];
  const float* bih0 = (const float*)d_in[9];
  const float* bhh0 = (const float*)d_in[10];
  const float* wih1 = (const float*)d_in[11];
  const float* whh1 = (const float*)d_in[12];
  const float* bih1 = (const float*)d_in[13];
  const float* bhh1 = (const float*)d_in[14];
  const float* out_w = (const float*)d_in[15];
  const float* out_b = (const float*)d_in[16];

  float* out  = (float*)d_out;
  float* ids  = out;                                  // [B,T]   4096
  float* msg  = out + 4096;                           // [B,T,V] 131072000
  float* logp = out + 131076096;                      // [B,T]   4096
  float* ent  = out + 131080192;                      // [B,T]   4096
  float* lens = out + 131084288;                      // [B]     256

  // scratch inside msg region (rewritten at the end); all float-count offsets
  float* p = msg;
  ushort* W30 = (ushort*)p; p += 1572864;             // 2048*1536 bf16
  ushort* W31 = (ushort*)p; p += 2097152;             // 2048*2048 bf16
  float* bq0 = p; p += 2048;
  float* bq1 = p; p += 2048;
  ushort* A0a = (ushort*)p; p += 196608;              // 256*1536 bf16
  ushort* A0b = (ushort*)p; p += 196608;
  ushort* A1a = (ushort*)p; p += 262144;              // 256*2048 bf16
  ushort* A1b = (ushort*)p; p += 262144;
  float* c0 = p; p += 131072;
  float* c1 = p; p += 131072;
  ushort* A2 = (ushort*)p; p += 131072;               // 256*1024 bf16
  ushort* B2 = (ushort*)p; p += 16384000;             // 32000*1024 bf16
  float* partials = p; p += 1024000;                  // 256*500*8
  uint32_t* keys = (uint32_t*)p; p += 64;
  int* done = (int*)p; p += 256;

  prepW3_kernel<<<2048, 256, 0, stream>>>(wih0, whh0, bih0, bhh0, W30, bq0, 256, keys);
  prepW3_kernel<<<2048, 256, 0, stream>>>(wih1, whh1, bih1, bhh1, W31, bq1, 512, nullptr);
  prepB2_kernel<<<4096, 256, 0, stream>>>(out_w, B2);
  backbone_kernel<<<256, 256, 0, stream>>>(x, bb_w, bb_b, ln_g, ln_b, sos,
                                           A0a, A1a, c0, c1, done);
  for (int t = 0; t < T_; ++t) {
    ushort* A0c = (t & 1) ? A0b : A0a;
    ushort* A0n = (t & 1) ? A0a : A0b;
    ushort* A1c = (t & 1) ? A1b : A1a;
    ushort* A1n = (t & 1) ? A1a : A1b;
    // cell 0 (K=768): h0 -> A1 cur (h0 hi/lo) + A0 next (h hi/lo)
    mfma_lstm<12><<<dim3(32, 8), 256, 0, stream>>>(
        A0c, W30, bq0, c0,
        A1c, 2048, 0, 1024,
        A0n, 1536, 256, 1024);
    // cell 1 (K=1024): h1 -> A1 next (h1 hi/lo) + A2 (logits input hi/lo)
    mfma_lstm<16><<<dim3(32, 8), 256, 0, stream>>>(
        A1c, W31, bq1, c1,
        A1n, 2048, 512, 1536,
        A2, 1024, 0, 512);
    // fused logits GEMM + pruned sampling partials (logits never materialized)
    mfma_sample<<<500, 256, 0, stream>>>(A2, B2, out_b, keys, t, partials);
    // merge: token, logp, ent, done, feedback (+lengths at t=15)
    merge_sample<<<256, 256, 0, stream>>>(partials, emb, t, done, A0n,
                                          ids, logp, ent, lens);
  }
  msg_kernel<<<4096, 256, 0, stream>>>(ids, msg);
}

// Round 11
// 1787.116 us; speedup vs baseline: 1.9228x; 1.9228x over previous
//
#include <hip/hip_runtime.h>
#include <cstdint>
#include <cmath>

#define B_ 256
#define T_ 16
#define V_ 32000
#define E_ 256
#define H_ 512

typedef __attribute__((ext_vector_type(8))) short bf16x8;
typedef __attribute__((ext_vector_type(4))) float f32x4;

// ---------------- Threefry-2x32 (JAX-compatible) ----------------
__device__ __forceinline__ uint32_t rotl32(uint32_t x, int r) {
  return (x << r) | (x >> (32 - r));
}

__device__ __forceinline__ void tf2x32(uint32_t k0, uint32_t k1, uint32_t x0, uint32_t x1,
                                       uint32_t& o0, uint32_t& o1) {
  uint32_t k2 = k0 ^ k1 ^ 0x1BD11BDAu;
  x0 += k0; x1 += k1;
#define TFR(r) { x0 += x1; x1 = rotl32(x1, (r)); x1 ^= x0; }
  TFR(13) TFR(15) TFR(26) TFR(6)   x0 += k1; x1 += k2 + 1u;
  TFR(17) TFR(29) TFR(16) TFR(24)  x0 += k2; x1 += k0 + 2u;
  TFR(13) TFR(15) TFR(26) TFR(6)   x0 += k0; x1 += k1 + 3u;
  TFR(17) TFR(29) TFR(16) TFR(24)  x0 += k1; x1 += k2 + 4u;
  TFR(13) TFR(15) TFR(26) TFR(6)   x0 += k2; x1 += k0 + 5u;
#undef TFR
  o0 = x0; o1 = x1;
}

// round f32 -> bf16 bits (RTNE), value assumed finite
__device__ __forceinline__ uint32_t f2bf(float x) {
  uint32_t u = __float_as_uint(x);
  return (u + 0x7fffu + ((u >> 16) & 1u)) >> 16;
}

typedef const __attribute__((address_space(1))) void* as1_t;
typedef __attribute__((address_space(3))) void* as3_t;
__device__ __forceinline__ void glds16(const void* g, void* l) {
  __builtin_amdgcn_global_load_lds((as1_t)g, (as3_t)l, 16, 0, 0);
}

// ---------------- prep_all: cell weights [hi|lo] + B2 [hi|lo] + bias sums + keys ----------
__global__ __launch_bounds__(256) void prep_all(
    const float* __restrict__ wih0, const float* __restrict__ whh0,
    const float* __restrict__ bih0, const float* __restrict__ bhh0,
    const float* __restrict__ wih1, const float* __restrict__ whh1,
    const float* __restrict__ bih1, const float* __restrict__ bhh1,
    const float* __restrict__ out_w,
    ushort* __restrict__ W30, ushort* __restrict__ W31,
    float* __restrict__ bq0, float* __restrict__ bq1,
    ushort* __restrict__ B2, uint32_t* __restrict__ keys)
{
  const long long stride = (long long)gridDim.x * blockDim.x;
  const long long i0 = (long long)blockIdx.x * blockDim.x + threadIdx.x;
  if (i0 < 16) {
    uint32_t o0, o1;
    tf2x32(0u, 1u, 0u, (uint32_t)i0, o0, o1);   // split(key(1), 16)
    keys[2 * i0] = o0; keys[2 * i0 + 1] = o1;
  }
  const long long S0 = 2048LL * 768;            // W30 elems
  const long long T1 = S0;
  const long long T2 = T1 + 2048LL * 1024;      // W31
  const long long T3 = T2 + 2048;               // bq0
  const long long T4 = T3 + 2048;               // bq1
  const long long T5 = T4 + 32000LL * 512;      // B2
  for (long long i = i0; i < T5; i += stride) {
    if (i < T1) {
      int n = (int)(i / 768), k = (int)(i % 768);
      int r = (n & 3) * 512 + (n >> 2);
      float x = (k < 256) ? wih0[(size_t)r * 256 + k] : whh0[(size_t)r * 512 + (k - 256)];
      uint32_t hi = f2bf(x);
      float hf = __uint_as_float(hi << 16);
      uint32_t lo = f2bf(x - hf);
      ushort* row = W30 + (size_t)n * 1536;
      row[k] = (ushort)hi; row[768 + k] = (ushort)lo;
    } else if (i < T2) {
      long long q = i - T1;
      int n = (int)(q / 1024), k = (int)(q % 1024);
      int r = (n & 3) * 512 + (n >> 2);
      float x = (k < 512) ? wih1[(size_t)r * 512 + k] : whh1[(size_t)r * 512 + (k - 512)];
      uint32_t hi = f2bf(x);
      float hf = __uint_as_float(hi << 16);
      uint32_t lo = f2bf(x - hf);
      ushort* row = W31 + (size_t)n * 2048;
      row[k] = (ushort)hi; row[1024 + k] = (ushort)lo;
    } else if (i < T3) {
      int n = (int)(i - T2);
      int r = (n & 3) * 512 + (n >> 2);
      bq0[n] = bih0[r] + bhh0[r];
    } else if (i < T4) {
      int n = (int)(i - T3);
      int r = (n & 3) * 512 + (n >> 2);
      bq1[n] = bih1[r] + bhh1[r];
    } else {
      long long q = i - T4;
      int n = (int)(q >> 9), k = (int)(q & 511);
      float x = out_w[q];
      uint32_t hi = f2bf(x);
      float hf = __uint_as_float(hi << 16);
      uint32_t lo = f2bf(x - hf);
      ushort* row = B2 + (size_t)n * 1024;
      row[k] = (ushort)hi; row[512 + k] = (ushort)lo;
    }
  }
}

// ---------------- backbone: Linear + LayerNorm + exact GELU, state init ----------------
// A0 row [x_hi(256)|h_hi(512)|x_lo(256)|h_lo(512)] stride 1536
// A1 row [h0_hi(512)|h1_hi(512)|h0_lo(512)|h1_lo(512)] stride 2048
__global__ __launch_bounds__(256) void backbone_kernel(
    const float* __restrict__ x, const float* __restrict__ bb_w, const float* __restrict__ bb_b,
    const float* __restrict__ ln_g, const float* __restrict__ ln_b, const float* __restrict__ sos,
    ushort* __restrict__ A0a, ushort* __restrict__ A1a,
    float* __restrict__ c0, float* __restrict__ c1, int* __restrict__ done)
{
  const int b = blockIdx.x, tid = threadIdx.x;
  __shared__ float xs[E_];
  __shared__ float zs[H_];
  __shared__ float red[256];
  xs[tid] = x[b * E_ + tid];
  __syncthreads();
  for (int jj = 0; jj < 2; ++jj) {
    int j = jj * 256 + tid;
    float acc = 0.0f;
#pragma unroll 4
    for (int k = 0; k < E_; ++k) acc = fmaf(xs[k], bb_w[(size_t)j * E_ + k], acc);
    zs[j] = acc + bb_b[j];
  }
  __syncthreads();
  red[tid] = zs[tid] + zs[tid + 256];
  __syncthreads();
  for (int off = 128; off > 0; off >>= 1) { if (tid < off) red[tid] += red[tid + off]; __syncthreads(); }
  const float mu = red[0] / 512.0f;
  __syncthreads();
  {
    float d0 = zs[tid] - mu, d1 = zs[tid + 256] - mu;
    red[tid] = d0 * d0 + d1 * d1;
  }
  __syncthreads();
  for (int off = 128; off > 0; off >>= 1) { if (tid < off) red[tid] += red[tid + off]; __syncthreads(); }
  const float var = red[0] / 512.0f;
  const float sv = sqrtf(var + 1e-5f);
  for (int jj = 0; jj < 2; ++jj) {
    int j = jj * 256 + tid;
    float zn = (zs[j] - mu) / sv * ln_g[j] + ln_b[j];
    float h = 0.5f * zn * (1.0f + erff(zn / 1.41421356237309515f));
    uint32_t hi = f2bf(h);
    float hf = __uint_as_float(hi << 16);
    uint32_t lo = f2bf(h - hf);
    A0a[(size_t)b * 1536 + 256 + j]  = (ushort)hi;   // h0 hi
    A0a[(size_t)b * 1536 + 1024 + j] = (ushort)lo;   // h0 lo
    A1a[(size_t)b * 2048 + 512 + j]  = 0;            // h1 hi = 0
    A1a[(size_t)b * 2048 + 1536 + j] = 0;            // h1 lo = 0
    c0[(size_t)b * 512 + j] = 0.0f;
    c1[(size_t)b * 512 + j] = 0.0f;
  }
  {
    const float xv = sos[tid];
    uint32_t hi = f2bf(xv);
    float hf = __uint_as_float(hi << 16);
    uint32_t lo = f2bf(xv - hf);
    A0a[(size_t)b * 1536 + tid]       = (ushort)hi;  // x hi
    A0a[(size_t)b * 1536 + 768 + tid] = (ushort)lo;  // x lo
  }
  if (tid == 0) done[b] = 0;
}

// ---------------- split-bf16 MFMA LSTM cell, 4-chunk rounds, double-buffered ----------------
// A3 [256][2K], W3 [2048][2K] bf16 [hi|lo]; K-chunk term map: A {hi,hi,lo}, W {hi,lo,hi}.
// 32x64 tile, grid (32,8)=256 blocks, 4 waves (2x2). Proven at 1799 us (r9).
template<int TK>
__global__ __launch_bounds__(256) void mfma_lstm(
    const ushort* __restrict__ A3, const ushort* __restrict__ W3,
    const float* __restrict__ bias, float* __restrict__ c,
    ushort* __restrict__ d1, int rs1, int o1h, int o1l,
    ushort* __restrict__ d2, int rs2, int o2h, int o2l)
{
  constexpr int K = TK * 64;
  constexpr int KC = 3 * TK;
  constexpr int NR = KC / 4;                 // 9 (cell0) / 12 (cell1)
  constexpr int RS = 2 * K;                  // row stride (ushorts)
  __shared__ __align__(16) char smem[98304];
  const int tid = threadIdx.x;
  const int lane = tid & 63;
  const int wid = tid >> 6;
  const int wm = wid >> 1, wn = wid & 1;
  const int m0 = blockIdx.y * 32;
  const int n0 = blockIdx.x * 64;

  auto stage_chunk = [&](int kc, char* cbase) {
    const int tI = kc / TK;
    const int kin = kc - tI * TK;
    const int abase = (tI == 2 ? K : 0) + kin * 64;
    const int wbase = (tI == 1 ? K : 0) + kin * 64;
    {  // A tile [32][64]: 4 KB, 1 load/thread
      const int o = wid * 1024 + lane * 16;
      const int row = o >> 7;
      const int kb = (o >> 4) & 7;
      glds16(A3 + (size_t)(m0 + row) * RS + abase + ((kb ^ (row & 7)) << 3),
             (void*)(cbase + wid * 1024));
    }
#pragma unroll
    for (int s = 0; s < 2; ++s) {  // W tile [64][64]: 8 KB, 2 loads/thread
      const int o = (wid * 2 + s) * 1024 + lane * 16;
      const int row = o >> 7;
      const int kb = (o >> 4) & 7;
      glds16(W3 + (size_t)(n0 + row) * RS + wbase + ((kb ^ (row & 7)) << 3),
             (void*)(cbase + 4096 + (wid * 2 + s) * 1024));
    }
  };
  auto stage_round = [&](int r, char* base) {
#pragma unroll
    for (int cch = 0; cch < 4; ++cch) stage_chunk(r * 4 + cch, base + cch * 12288);
  };

  f32x4 acc[2];
#pragma unroll
  for (int j = 0; j < 2; ++j)
#pragma unroll
    for (int q = 0; q < 4; ++q) acc[j][q] = 0.0f;

  stage_round(0, smem);
  asm volatile("s_waitcnt vmcnt(0)" ::: "memory");
  __syncthreads();
  for (int r = 0; r < NR; ++r) {
    char* cur = smem + (r & 1) * 49152;
    if (r + 1 < NR) stage_round(r + 1, smem + ((r + 1) & 1) * 49152);
#pragma unroll
    for (int cch = 0; cch < 4; ++cch) {
      char* lds = cur + cch * 12288;
#pragma unroll
      for (int ks = 0; ks < 2; ++ks) {
        const int kb = ks * 4 + (lane >> 4);
        const int arow = wm * 16 + (lane & 15);
        bf16x8 a = *(const bf16x8*)(lds + arow * 128 + ((kb ^ (arow & 7)) << 4));
        bf16x8 w[2];
#pragma unroll
        for (int j = 0; j < 2; ++j) {
          const int col = wn * 32 + j * 16 + (lane & 15);
          w[j] = *(const bf16x8*)(lds + 4096 + col * 128 + ((kb ^ (col & 7)) << 4));
        }
#pragma unroll
        for (int j = 0; j < 2; ++j)
          acc[j] = __builtin_amdgcn_mfma_f32_16x16x32_bf16(a, w[j], acc[j], 0, 0, 0);
      }
    }
    asm volatile("s_waitcnt vmcnt(0)" ::: "memory");
    __syncthreads();
  }
  // gate transpose via LDS (f32 [32][65], aliases buf0 — all staging/compute done)
  float* gls = (float*)smem;
#pragma unroll
  for (int j = 0; j < 2; ++j)
#pragma unroll
    for (int q = 0; q < 4; ++q)
      gls[(wm * 16 + (lane >> 4) * 4 + q) * 65 + wn * 32 + j * 16 + (lane & 15)] = acc[j][q];
  __syncthreads();
  const int row = tid >> 3;                  // 0..31
  const int m = m0 + row;
#pragma unroll
  for (int e = 0; e < 2; ++e) {
    const int ul = (tid & 7) * 2 + e;        // local unit 0..15
    const int nc = ul * 4;
    const float gi = gls[row * 65 + nc + 0] + bias[n0 + nc + 0];
    const float gf = gls[row * 65 + nc + 1] + bias[n0 + nc + 1];
    const float gg = gls[row * 65 + nc + 2] + bias[n0 + nc + 2];
    const float go = gls[row * 65 + nc + 3] + bias[n0 + nc + 3];
    const int u = (n0 >> 2) + ul;            // global hidden unit
    const float si = 1.0f / (1.0f + expf(-gi));
    const float sf = 1.0f / (1.0f + expf(-gf));
    const float so = 1.0f / (1.0f + expf(-go));
    const float cn = sf * c[(size_t)m * 512 + u] + si * tanhf(gg);
    const float hn = so * tanhf(cn);
    c[(size_t)m * 512 + u] = cn;
    const uint32_t hi = f2bf(hn);
    const float hf = __uint_as_float(hi << 16);
    const uint32_t lo = f2bf(hn - hf);
    d1[(size_t)m * rs1 + o1h + u] = (ushort)hi;
    d1[(size_t)m * rs1 + o1l + u] = (ushort)lo;
    d2[(size_t)m * rs2 + o2h + u] = (ushort)hi;
    d2[(size_t)m * rs2 + o2l + u] = (ushort)lo;
  }
}

// ---------------- bf16 MFMA logits GEMM, dbuf 2-phase, 8 waves (2m x 4n) ----------------
// A2 [256][1024] (term map {hi,hi,lo}), B2 [32000][1024] (term map {hi,lo,hi}).
// 128x128 tile, 512 threads: 16 waves/CU (was 8) for latency hiding. Same math/order.
__global__ __launch_bounds__(512) void mfma_logits(
    const ushort* __restrict__ A2,
    const ushort* __restrict__ B2,
    const float* __restrict__ bias,
    float* __restrict__ logits)      // [256][32000] f32
{
  __shared__ __align__(16) char smem[65536];
  char* lds = smem;
  const int tid = threadIdx.x;
  const int lane = tid & 63;
  const int wid = tid >> 6;          // 0..7
  const int wm = wid >> 2, wn = wid & 3;
  // bijective XCD swizzle (nwg=500: q=62, r=4), then m-blocks of a panel adjacent
  const int bid = blockIdx.x;
  const int xcd = bid & 7, idx = bid >> 3;
  const int wg = (xcd < 4 ? xcd * 63 : 252 + (xcd - 4) * 62) + idx;
  const int m0 = (wg & 1) * 128;
  const int n0 = (wg >> 1) * 128;

  auto stage = [&](int kc, int base) {
    const int tI = kc >> 3;
    const int kin = kc & 7;
    const int abase = (tI == 2 ? 512 : 0) + kin * 64;
    const int bbase = (tI == 1 ? 512 : 0) + kin * 64;
#pragma unroll
    for (int s = 0; s < 2; ++s) {
      const int o = (wid * 2 + s) * 1024 + lane * 16;
      const int row = o >> 7;
      const int kb = (o >> 4) & 7;
      const int sw = (kb ^ (row & 7)) << 3;
      glds16(A2 + (size_t)(m0 + row) * 1024 + abase + sw,
             (void*)(lds + base + (wid * 2 + s) * 1024));
      glds16(B2 + (size_t)(n0 + row) * 1024 + bbase + sw,
             (void*)(lds + base + 16384 + (wid * 2 + s) * 1024));
    }
  };

  f32x4 acc[4][2];
#pragma unroll
  for (int i = 0; i < 4; ++i)
#pragma unroll
    for (int j = 0; j < 2; ++j)
#pragma unroll
      for (int q = 0; q < 4; ++q) acc[i][j][q] = 0.0f;

  stage(0, 0);
  asm volatile("s_waitcnt vmcnt(0)" ::: "memory");
  __syncthreads();
  for (int kc = 0; kc < 24; ++kc) {
    const int cb = (kc & 1) * 32768;
    if (kc + 1 < 24) stage(kc + 1, cb ^ 32768);
#pragma unroll
    for (int ks = 0; ks < 2; ++ks) {
      bf16x8 a[4], b[2];
      const int kb = ks * 4 + (lane >> 4);
#pragma unroll
      for (int i = 0; i < 4; ++i) {
        const int row = wm * 64 + i * 16 + (lane & 15);
        a[i] = *(const bf16x8*)(lds + cb + row * 128 + ((kb ^ (row & 7)) << 4));
      }
#pragma unroll
      for (int j = 0; j < 2; ++j) {
        const int col = wn * 32 + j * 16 + (lane & 15);
        b[j] = *(const bf16x8*)(lds + cb + 16384 + col * 128 + ((kb ^ (col & 7)) << 4));
      }
#pragma unroll
      for (int i = 0; i < 4; ++i)
#pragma unroll
        for (int j = 0; j < 2; ++j)
          acc[i][j] = __builtin_amdgcn_mfma_f32_16x16x32_bf16(a[i], b[j], acc[i][j], 0, 0, 0);
    }
    asm volatile("s_waitcnt vmcnt(0)" ::: "memory");
    __syncthreads();
  }
  const int lsub = lane & 15;
  float bj[2];
#pragma unroll
  for (int j = 0; j < 2; ++j) bj[j] = bias[n0 + wn * 32 + j * 16 + lsub];
  const int rbase = (lane >> 4) * 4;
#pragma unroll
  for (int i = 0; i < 4; ++i) {
    const int m = m0 + wm * 64 + i * 16 + rbase;
#pragma unroll
    for (int j = 0; j < 2; ++j) {
      const int n = n0 + wn * 32 + j * 16 + lsub;
#pragma unroll
      for (int q = 0; q < 4; ++q)
        logits[(size_t)(m + q) * V_ + n] = acc[i][j][q] + bj[j];
    }
  }
}

// ---------------- sample_row: one pass (m=0) with pruned gumbel, fused feedback ----------
// Prune: s = l - log(-log u) < th  ⟺  u < exp(-exp(-(th-l))); th = wave-max of exact bests.
// Margin 1e-3 covers double-log vs real-log error + f32 roundings; strict < means pruned
// elements can never win or tie -> token selection bit-identical. Proven r9 (1799 us).
__global__ __launch_bounds__(512) void sample_row(
    const float* __restrict__ logits, const uint32_t* __restrict__ keys, int t,
    const float* __restrict__ emb, int* __restrict__ done,
    ushort* __restrict__ A0next, float* __restrict__ ids,
    float* __restrict__ logp, float* __restrict__ ent, float* __restrict__ lens)
{
  const int b = blockIdx.x, tid = threadIdx.x;
  const uint32_t k0 = keys[2 * t], k1 = keys[2 * t + 1];
  const float* lrow = logits + (size_t)b * V_;

  float S = 0.0f, Aa = 0.0f, sb = -INFINITY, lb = 0.0f; int ib = 0;
  float th = -INFINITY;
  int it = 0;
  for (int idx = tid; idx < V_ / 4; idx += 512, ++it) {
    float4 l4 = *(const float4*)&lrow[idx * 4];
    const float le[4] = {l4.x, l4.y, l4.z, l4.w};
#pragma unroll
    for (int e = 0; e < 4; ++e) {
      const int v = idx * 4 + e;
      uint32_t o0, o1;
      tf2x32(k0, k1, 0u, (uint32_t)(b * V_ + v), o0, o1);
      const uint32_t man = (o0 ^ o1) >> 9;
      const float u = (man == 0u) ? 1.17549435e-38f
                                  : __uint_as_float(man | 0x3f800000u) - 1.0f;
      const float ex = expf(le[e]);           // |l| small: no overflow, m=0
      S += ex; Aa = fmaf(ex, le[e], Aa);
      const float thl = fmaxf(th, sb);
      bool need = true;
      if (thl > -1e30f) {
        const float uth = __expf(-__expf(-(thl - le[e] - 1e-3f)));
        need = (u >= uth);
      }
      if (need) {
        const float inner = (float)log((double)u);       // < 0
        const float outer = (float)log((double)(-inner));
        const float s = le[e] - outer;
        if (s > sb) { sb = s; ib = v; lb = le[e]; }
      }
    }
    if (it == 0 || it == 3) {                 // wave-share threshold
      float m2 = sb;
#pragma unroll
      for (int o = 1; o < 64; o <<= 1) m2 = fmaxf(m2, __shfl_xor(m2, o));
      th = m2;
    }
  }
  __shared__ float ss[512], sa[512], sv[512], sl[512];
  __shared__ int si[512];
  ss[tid] = S; sa[tid] = Aa; sv[tid] = sb; si[tid] = ib; sl[tid] = lb;
  __syncthreads();
  for (int o = 256; o > 0; o >>= 1) {
    if (tid < o) {
      ss[tid] += ss[tid + o]; sa[tid] += sa[tid + o];
      float v2 = sv[tid + o]; int i2 = si[tid + o];
      if (v2 > sv[tid] || (v2 == sv[tid] && i2 < si[tid])) {
        sv[tid] = v2; si[tid] = i2; sl[tid] = sl[tid + o];
      }
    }
    __syncthreads();
  }
  if (tid == 0) {
    const float Ssum = ss[0], Asum = sa[0];
    const float logS = logf(Ssum);
    const int tok = si[0];
    const float lp = sl[0] - logS;
    const float en = logS - Asum / Ssum;
    const int dn = done[b];
    const int tokm = dn ? 0 : tok;
    ids[b * T_ + t]  = (float)tokm;
    logp[b * T_ + t] = dn ? 0.0f : lp;
    ent[b * T_ + t]  = dn ? 0.0f : en;
    done[b] = dn | (tokm == 0);
    si[0] = tokm;
    if (t == T_ - 1) {
      int len = T_; bool has = false;
      for (int tt = 0; tt < T_; ++tt) {
        if (!has && ids[b * T_ + tt] == 0.0f) { has = true; len = tt + 1; }
      }
      for (int tt = len - 1; tt < T_; ++tt) ids[b * T_ + tt] = 0.0f;
      lens[b] = (float)len;
    }
  }
  __syncthreads();
  const int tk = si[0];
  if (tid < E_) {
    const float xv = emb[(size_t)tk * E_ + tid];
    const uint32_t hi = f2bf(xv);
    const float hf = __uint_as_float(hi << 16);
    const uint32_t lo = f2bf(xv - hf);
    A0next[(size_t)b * 1536 + tid]       = (ushort)hi;
    A0next[(size_t)b * 1536 + 768 + tid] = (ushort)lo;
  }
}

// ---------------- one-hot msg fill ----------------
__global__ __launch_bounds__(256) void msg_kernel(const float* __restrict__ ids,
                                                  float* __restrict__ msg) {
  const int bt = blockIdx.x;            // 4096 = B*T
  const int id = (int)ids[bt];
  float4* dst = (float4*)(msg + (size_t)bt * V_);
  for (int q = threadIdx.x; q < V_ / 4; q += 256) {
    const int v = q * 4;
    float4 val;
    val.x = (v     == id) ? 1.0f : 0.0f;
    val.y = (v + 1 == id) ? 1.0f : 0.0f;
    val.z = (v + 2 == id) ? 1.0f : 0.0f;
    val.w = (v + 3 == id) ? 1.0f : 0.0f;
    dst[q] = val;
  }
}

// ---------------- launcher ----------------
extern "C" void kernel_launch(void* const* d_in, const int* in_sizes, int n_in,
                              void* d_out, int out_size, void* d_ws, size_t ws_size,
                              hipStream_t stream) {
  const float* x    = (const float*)d_in[0];
  const float* bb_w = (const float*)d_in[1];
  const float* bb_b = (const float*)d_in[2];
  const float* ln_g = (const float*)d_in[3];
  const float* ln_b = (const float*)d_in[4];
  const float* emb  = (const float*)d_in[5];
  const float* sos  = (const float*)d_in[6];
  const float* wih0 = (const float*)d_in[7];
  const float* whh0 = (const float*)d_in[8];
  const float* bih0 = (const float*)d_in[9];
  const float* bhh0 = (const float*)d_in[10];
  const float* wih1 = (const float*)d_in[11];
  const float* whh1 = (const float*)d_in[12];
  const float* bih1 = (const float*)d_in[13];
  const float* bhh1 = (const float*)d_in[14];
  const float* out_w = (const float*)d_in[15];
  const float* out_b = (const float*)d_in[16];

  float* out  = (float*)d_out;
  float* ids  = out;                                  // [B,T]   4096
  float* msg  = out + 4096;                           // [B,T,V] 131072000
  float* logp = out + 131076096;                      // [B,T]   4096
  float* ent  = out + 131080192;                      // [B,T]   4096
  float* lens = out + 131084288;                      // [B]     256

  // scratch inside msg region (rewritten at the end); all float-count offsets
  float* p = msg;
  ushort* W30 = (ushort*)p; p += 1572864;             // 2048*1536 bf16
  ushort* W31 = (ushort*)p; p += 2097152;             // 2048*2048 bf16
  float* bq0 = p; p += 2048;
  float* bq1 = p; p += 2048;
  ushort* A0a = (ushort*)p; p += 196608;              // 256*1536 bf16
  ushort* A0b = (ushort*)p; p += 196608;
  ushort* A1a = (ushort*)p; p += 262144;              // 256*2048 bf16
  ushort* A1b = (ushort*)p; p += 262144;
  float* c0 = p; p += 131072;
  float* c1 = p; p += 131072;
  ushort* A2 = (ushort*)p; p += 131072;               // 256*1024 bf16
  ushort* B2 = (ushort*)p; p += 16384000;             // 32000*1024 bf16
  float* logits = p; p += 8192000;                    // 256*32000 f32
  uint32_t* keys = (uint32_t*)p; p += 64;
  int* done = (int*)p; p += 256;

  prep_all<<<4096, 256, 0, stream>>>(wih0, whh0, bih0, bhh0,
                                     wih1, whh1, bih1, bhh1, out_w,
                                     W30, W31, bq0, bq1, B2, keys);
  backbone_kernel<<<256, 256, 0, stream>>>(x, bb_w, bb_b, ln_g, ln_b, sos,
                                           A0a, A1a, c0, c1, done);
  for (int t = 0; t < T_; ++t) {
    ushort* A0c = (t & 1) ? A0b : A0a;
    ushort* A0n = (t & 1) ? A0a : A0b;
    ushort* A1c = (t & 1) ? A1b : A1a;
    ushort* A1n = (t & 1) ? A1a : A1b;
    // cell 0 (K=768): h0 -> A1 cur (h0 hi/lo) + A0 next (h hi/lo)
    mfma_lstm<12><<<dim3(32, 8), 256, 0, stream>>>(
        A0c, W30, bq0, c0,
        A1c, 2048, 0, 1024,
        A0n, 1536, 256, 1024);
    // cell 1 (K=1024): h1 -> A1 next (h1 hi/lo) + A2 (logits input hi/lo)
    mfma_lstm<16><<<dim3(32, 8), 256, 0, stream>>>(
        A1c, W31, bq1, c1,
        A1n, 2048, 512, 1536,
        A2, 1024, 0, 512);
    // logits (f32, materialized), dbuf, 8 waves/block
    mfma_logits<<<500, 512, 0, stream>>>(A2, B2, out_b, logits);
    // fused sampling: pruned-gumbel argmax + softmax stats + feedback (+lengths at t=15)
    sample_row<<<256, 512, 0, stream>>>(logits, keys, t, emb, done,
                                        A0n, ids, logp, ent, lens);
  }
  msg_kernel<<<4096, 256, 0, stream>>>(ids, msg);
}